// Round 4
// baseline (1386.311 us; speedup 1.0000x reference)
//
#include <hip/hip_runtime.h>
#include <math.h>

#define HIDDEN 1024
#define HEADS 16
#define HDIM 64
#define BATCH 2
#define SEQ 2048
#define NEGV -1.0e9f
#define TOK (BATCH * SEQ * HIDDEN)            // 4,194,304
#define HH (HIDDEN * HIDDEN)                  // 1,048,576
#define SC_N ((size_t)BATCH * HEADS * SEQ * SEQ)  // 134,217,728
#define ROW_CUT 29
#define PIT 72   // LDS pitch in bf16 elems: 144B rows -> 16B aligned, 4*row banks spread

typedef __bf16 bf16x8 __attribute__((ext_vector_type(8)));
typedef float f32x4 __attribute__((ext_vector_type(4)));

__device__ __forceinline__ unsigned short f2bf(float f) {
    union { float f; unsigned u; } v; v.f = f;
    unsigned r = (v.u + 0x7fffu + ((v.u >> 16) & 1u)) >> 16;
    return (unsigned short)r;
}
__device__ __forceinline__ float bf2f(unsigned short h) {
    union { unsigned u; float f; } v; v.u = ((unsigned)h) << 16;
    return v.f;
}
__device__ __forceinline__ void split_bf(float v, unsigned short& h, unsigned short& l) {
    h = f2bf(v);
    l = f2bf(v - bf2f(h));
}
__device__ __forceinline__ bf16x8 ld_frag(const unsigned short* p) {
    union { uint4 u; bf16x8 v; } t;
    t.u = *(const uint4*)p;
    return t.v;
}

// ---------------- split fp32 array -> (hi, lo) bf16, same layout. n = count, 8/thread.
__global__ __launch_bounds__(256) void split_rows(const float* __restrict__ in,
    unsigned short* __restrict__ hi, unsigned short* __restrict__ lo)
{
    size_t i = ((size_t)blockIdx.x * 256 + threadIdx.x) * 8;
    float4 f0 = *(const float4*)(in + i);
    float4 f1 = *(const float4*)(in + i + 4);
    union { uint4 u; unsigned short s[8]; } H, L;
    split_bf(f0.x, H.s[0], L.s[0]); split_bf(f0.y, H.s[1], L.s[1]);
    split_bf(f0.z, H.s[2], L.s[2]); split_bf(f0.w, H.s[3], L.s[3]);
    split_bf(f1.x, H.s[4], L.s[4]); split_bf(f1.y, H.s[5], L.s[5]);
    split_bf(f1.z, H.s[6], L.s[6]); split_bf(f1.w, H.s[7], L.s[7]);
    *(uint4*)(hi + i) = H.u;
    *(uint4*)(lo + i) = L.u;
}

// ---------------- split + transpose: W[K][N] fp32 -> WT(hi,lo)[N][K] bf16. 64x64 tiles.
__global__ __launch_bounds__(256) void split_T(const float* __restrict__ W,
    unsigned short* __restrict__ Thi, unsigned short* __restrict__ Tlo)
{
    __shared__ float Ts[64][65];
    int n0 = blockIdx.x * 64, k0 = blockIdx.y * 64;
    int tid = threadIdx.x;
    int r = tid >> 4, c4 = (tid & 15) * 4;
    #pragma unroll
    for (int i = 0; i < 4; i++) {
        int rr = r + i * 16;
        float4 f = *(const float4*)&W[(size_t)(k0 + rr) * HIDDEN + n0 + c4];
        Ts[rr][c4 + 0] = f.x; Ts[rr][c4 + 1] = f.y;
        Ts[rr][c4 + 2] = f.z; Ts[rr][c4 + 3] = f.w;
    }
    __syncthreads();
    int rp = tid >> 3, g = tid & 7;
    #pragma unroll
    for (int i = 0; i < 2; i++) {
        int nr = rp + i * 32;     // output row (n), cols k0+g*8..+7
        union { uint4 u; unsigned short s[8]; } Hh, Ll;
        #pragma unroll
        for (int d = 0; d < 8; d++)
            split_bf(Ts[g * 8 + d][nr], Hh.s[d], Ll.s[d]);
        size_t o = (size_t)(n0 + nr) * HIDDEN + k0 + g * 8;
        *(uint4*)&Thi[o] = Hh.u;
        *(uint4*)&Tlo[o] = Ll.u;
    }
}

// ---------------- presplit MFMA GEMM: C[M,N] = A[M,K] @ BT[N,K]^T + bias.
// A as (Ahi,Alo) [M][K]; B as (BThi,BTlo) [N][K] (pre-transposed). BM=BN=128, BK=64,
// 512 threads = 8 waves (2M x 4N), wave tile 64x32. Staging = pure uint4 copies.
template<int SPLITOUT>
__global__ __launch_bounds__(512) void gemm_ps(
    const unsigned short* __restrict__ Ahi, const unsigned short* __restrict__ Alo,
    const unsigned short* __restrict__ BThi, const unsigned short* __restrict__ BTlo,
    const float* __restrict__ bias, float* __restrict__ C,
    unsigned short* __restrict__ Ohi, unsigned short* __restrict__ Olo,
    int M, int N, int K)
{
    __shared__ unsigned short Ah[128][PIT], Al[128][PIT];
    __shared__ unsigned short Bh[128][PIT], Bl[128][PIT];
    int tid = threadIdx.x;
    int lane = tid & 63, wv = tid >> 6;
    int wm = wv >> 2, wn = wv & 3;
    int l15 = lane & 15, l4 = lane >> 4;
    int mBase = blockIdx.y * 128, nBase = blockIdx.x * 128;
    int sr = tid >> 3, sg = tid & 7;   // staging: 64 rows x 8 col-groups (x2)

    f32x4 acc[4][2] = {};

    for (int kt = 0; kt < K; kt += 64) {
        #pragma unroll
        for (int i = 0; i < 2; i++) {
            int rr = sr + i * 64;
            size_t ga = (size_t)(mBase + rr) * K + kt + sg * 8;
            *(uint4*)&Ah[rr][sg * 8] = *(const uint4*)&Ahi[ga];
            *(uint4*)&Al[rr][sg * 8] = *(const uint4*)&Alo[ga];
            size_t gb = (size_t)(nBase + rr) * K + kt + sg * 8;
            *(uint4*)&Bh[rr][sg * 8] = *(const uint4*)&BThi[gb];
            *(uint4*)&Bl[rr][sg * 8] = *(const uint4*)&BTlo[gb];
        }
        __syncthreads();

        #pragma unroll
        for (int ks = 0; ks < 64; ks += 32) {
            int ko = ks + l4 * 8;
            bf16x8 aH[4], aL[4], bH[2], bL[2];
            #pragma unroll
            for (int ti = 0; ti < 4; ti++) {
                aH[ti] = ld_frag(&Ah[wm * 64 + ti * 16 + l15][ko]);
                aL[ti] = ld_frag(&Al[wm * 64 + ti * 16 + l15][ko]);
            }
            #pragma unroll
            for (int tj = 0; tj < 2; tj++) {
                bH[tj] = ld_frag(&Bh[wn * 32 + tj * 16 + l15][ko]);
                bL[tj] = ld_frag(&Bl[wn * 32 + tj * 16 + l15][ko]);
            }
            #pragma unroll
            for (int ti = 0; ti < 4; ti++)
                #pragma unroll
                for (int tj = 0; tj < 2; tj++) {
                    acc[ti][tj] = __builtin_amdgcn_mfma_f32_16x16x32_bf16(aH[ti], bH[tj], acc[ti][tj], 0, 0, 0);
                    acc[ti][tj] = __builtin_amdgcn_mfma_f32_16x16x32_bf16(aH[ti], bL[tj], acc[ti][tj], 0, 0, 0);
                    acc[ti][tj] = __builtin_amdgcn_mfma_f32_16x16x32_bf16(aL[ti], bH[tj], acc[ti][tj], 0, 0, 0);
                }
        }
        __syncthreads();
    }

    #pragma unroll
    for (int ti = 0; ti < 4; ti++) {
        #pragma unroll
        for (int tj = 0; tj < 2; tj++) {
            int m0 = mBase + wm * 64 + ti * 16 + l4 * 4;
            int n  = nBase + wn * 32 + tj * 16 + l15;
            float bv = bias[n];
            #pragma unroll
            for (int rg = 0; rg < 4; rg++) {
                float v = acc[ti][tj][rg] + bv;
                if (SPLITOUT) {
                    unsigned short hh, ll;
                    split_bf(v, hh, ll);
                    Ohi[(size_t)(m0 + rg) * N + n] = hh;
                    Olo[(size_t)(m0 + rg) * N + n] = ll;
                } else {
                    C[(size_t)(m0 + rg) * N + n] = v;
                }
            }
        }
    }
}

// ---------------- MFMA attention v2: QBLK=128, 4 waves x 2 row-tiles (16 rows each).
// K row-major; V transposed with XOR block-swizzle (conflict-free both sides);
// K/V/P fragment reads amortized over 2 row-tiles.
__global__ __launch_bounds__(256) void attn_mfma(
    const unsigned short* __restrict__ Qhi, const unsigned short* __restrict__ Qlo,
    const unsigned short* __restrict__ Khi, const unsigned short* __restrict__ Klo,
    const unsigned short* __restrict__ Vhi, const unsigned short* __restrict__ Vlo,
    const int* __restrict__ mask, float* __restrict__ scores_out,
    unsigned short* __restrict__ Chi, unsigned short* __restrict__ Clo)
{
    __shared__ unsigned short Kh[64][PIT], Kl[64][PIT];
    __shared__ unsigned short Th[64][PIT], Tl[64][PIT];   // V^T [d][k], k blocks XOR-swizzled
    __shared__ unsigned short Ph[4][32][PIT], Pl[4][32][PIT];

    int tid = threadIdx.x;
    int lane = tid & 63, w = tid >> 6;
    int l15 = lane & 15, l4 = lane >> 4;
    int qBase = blockIdx.x * 128;
    int h = blockIdx.y, b = blockIdx.z;
    int sr = tid >> 3, sg = tid & 7;

    // Q fragments: 2 row-tiles x 2 k-chunks, hi/lo
    bf16x8 qh[2][2], ql[2][2];
    #pragma unroll
    for (int rt = 0; rt < 2; rt++) {
        size_t qofs = (size_t)(b * SEQ + qBase + w * 32 + rt * 16 + l15) * HIDDEN + h * HDIM;
        qh[rt][0] = ld_frag(&Qhi[qofs + l4 * 8]);
        qh[rt][1] = ld_frag(&Qhi[qofs + 32 + l4 * 8]);
        ql[rt][0] = ld_frag(&Qlo[qofs + l4 * 8]);
        ql[rt][1] = ld_frag(&Qlo[qofs + 32 + l4 * 8]);
    }

    f32x4 cacc[2][4] = {};
    float mrow[2][4] = {{-3.0e38f,-3.0e38f,-3.0e38f,-3.0e38f},
                        {-3.0e38f,-3.0e38f,-3.0e38f,-3.0e38f}};
    float rsum[2][4] = {};

    for (int kt = 0; kt < SEQ; kt += 64) {
        // ---- stage K rows + V^T (swizzled columns)
        #pragma unroll
        for (int i = 0; i < 2; i++) {
            int rr = sr + i * 32;
            size_t tok = (size_t)(b * SEQ + kt + rr) * HIDDEN + h * HDIM + sg * 8;
            *(uint4*)&Kh[rr][sg * 8] = *(const uint4*)&Khi[tok];
            *(uint4*)&Kl[rr][sg * 8] = *(const uint4*)&Klo[tok];
            union { uint4 u; unsigned short s[8]; } vh, vl;
            vh.u = *(const uint4*)&Vhi[tok];
            vl.u = *(const uint4*)&Vlo[tok];
            int cbs = ((((rr >> 3) ^ sg) & 7) << 3) + (rr & 7);
            #pragma unroll
            for (int dd = 0; dd < 8; dd++) {
                Th[sg * 8 + dd][cbs] = vh.s[dd];
                Tl[sg * 8 + dd][cbs] = vl.s[dd];
            }
        }
        __syncthreads();

        // ---- S strips = Q K^T: K frags shared across both row-tiles
        f32x4 sacc[2][4] = {};
        #pragma unroll
        for (int ks = 0; ks < 2; ks++) {
            int ko = ks * 32 + l4 * 8;
            #pragma unroll
            for (int j = 0; j < 4; j++) {
                bf16x8 kH = ld_frag(&Kh[j * 16 + l15][ko]);
                bf16x8 kL = ld_frag(&Kl[j * 16 + l15][ko]);
                #pragma unroll
                for (int rt = 0; rt < 2; rt++) {
                    sacc[rt][j] = __builtin_amdgcn_mfma_f32_16x16x32_bf16(qh[rt][ks], kH, sacc[rt][j], 0, 0, 0);
                    sacc[rt][j] = __builtin_amdgcn_mfma_f32_16x16x32_bf16(qh[rt][ks], kL, sacc[rt][j], 0, 0, 0);
                    sacc[rt][j] = __builtin_amdgcn_mfma_f32_16x16x32_bf16(ql[rt][ks], kH, sacc[rt][j], 0, 0, 0);
                }
            }
        }

        // ---- mask + scale + score write + online softmax + P split, per row-tile
        #pragma unroll
        for (int rt = 0; rt < 2; rt++) {
            float sv[4][4];
            #pragma unroll
            for (int j = 0; j < 4; j++) {
                #pragma unroll
                for (int rg = 0; rg < 4; rg++) {
                    int qrow = qBase + w * 32 + rt * 16 + l4 * 4 + rg;
                    int kc = kt + j * 16 + l15;
                    int mval = mask[(size_t)(b * SEQ + qrow) * SEQ + kc];
                    float s = (mval == 0) ? NEGV : sacc[rt][j][rg] * 0.125f;
                    scores_out[((size_t)(b * HEADS + h) * SEQ + qrow) * SEQ + kc] = s;
                    sv[j][rg] = s;
                }
            }
            #pragma unroll
            for (int rg = 0; rg < 4; rg++) {
                float tmax = fmaxf(fmaxf(sv[0][rg], sv[1][rg]), fmaxf(sv[2][rg], sv[3][rg]));
                #pragma unroll
                for (int o = 1; o < 16; o <<= 1)
                    tmax = fmaxf(tmax, __shfl_xor(tmax, o, 64));
                float mn = fmaxf(mrow[rt][rg], tmax);
                float fac = __expf(mrow[rt][rg] - mn);
                mrow[rt][rg] = mn;
                float ts = 0.f;
                #pragma unroll
                for (int j = 0; j < 4; j++) {
                    float e = __expf(sv[j][rg] - mn);
                    unsigned short ph, pl;
                    split_bf(e, ph, pl);
                    Ph[w][rt * 16 + l4 * 4 + rg][j * 16 + l15] = ph;
                    Pl[w][rt * 16 + l4 * 4 + rg][j * 16 + l15] = pl;
                    ts += e;
                }
                #pragma unroll
                for (int o = 1; o < 16; o <<= 1)
                    ts += __shfl_xor(ts, o, 64);
                rsum[rt][rg] = rsum[rt][rg] * fac + ts;
                cacc[rt][0][rg] *= fac; cacc[rt][1][rg] *= fac;
                cacc[rt][2][rg] *= fac; cacc[rt][3][rg] *= fac;
            }
        }

        // ---- ctx += P V (V frags shared across row-tiles; swizzled read)
        #pragma unroll
        for (int ks = 0; ks < 2; ks++) {
            int ko = ks * 32 + l4 * 8;
            bf16x8 pH[2], pL[2];
            #pragma unroll
            for (int rt = 0; rt < 2; rt++) {
                pH[rt] = ld_frag(&Ph[w][rt * 16 + l15][ko]);
                pL[rt] = ld_frag(&Pl[w][rt * 16 + l15][ko]);
            }
            #pragma unroll
            for (int j = 0; j < 4; j++) {
                int drow = j * 16 + l15;
                int pb = (((ko >> 3) ^ (drow >> 3)) & 7) << 3;
                bf16x8 vH = ld_frag(&Th[drow][pb]);
                bf16x8 vL = ld_frag(&Tl[drow][pb]);
                #pragma unroll
                for (int rt = 0; rt < 2; rt++) {
                    cacc[rt][j] = __builtin_amdgcn_mfma_f32_16x16x32_bf16(pH[rt], vH, cacc[rt][j], 0, 0, 0);
                    cacc[rt][j] = __builtin_amdgcn_mfma_f32_16x16x32_bf16(pH[rt], vL, cacc[rt][j], 0, 0, 0);
                    cacc[rt][j] = __builtin_amdgcn_mfma_f32_16x16x32_bf16(pL[rt], vH, cacc[rt][j], 0, 0, 0);
                }
            }
        }
        __syncthreads();
    }

    // ---- epilogue: ctx split-write
    #pragma unroll
    for (int rt = 0; rt < 2; rt++) {
        #pragma unroll
        for (int rg = 0; rg < 4; rg++) {
            float inv = 1.0f / rsum[rt][rg];
            int qrow = qBase + w * 32 + rt * 16 + l4 * 4 + rg;
            size_t obase = (size_t)(b * SEQ + qrow) * HIDDEN + h * HDIM;
            #pragma unroll
            for (int j = 0; j < 4; j++) {
                float v = cacc[rt][j][rg] * inv;
                unsigned short hh, ll;
                split_bf(v, hh, ll);
                Chi[obase + j * 16 + l15] = hh;
                Clo[obase + j * 16 + l15] = ll;
            }
        }
    }
}

// ================= fp32 fallback path (used only if ws too small) =================
__global__ __launch_bounds__(256) void gemm_bias(const float* __restrict__ A,
    const float* __restrict__ Bw, const float* __restrict__ bias,
    float* __restrict__ C, int M, int N, int K)
{
    __shared__ float As[64][17];
    __shared__ float Bs[16][65];
    int tid = threadIdx.x;
    int tx = tid & 15, ty = tid >> 4;
    int mBase = blockIdx.y * 64, nBase = blockIdx.x * 64;
    float acc[4][4] = {};
    int idA = tid * 4;
    int ra = idA >> 4, ca = idA & 15;
    int rb = idA >> 6, cb = idA & 63;
    int ty4 = ty * 4, tx4 = tx * 4;
    for (int k0 = 0; k0 < K; k0 += 16) {
        float4 fa = *(const float4*)(A + (size_t)(mBase + ra) * K + k0 + ca);
        As[ra][ca + 0] = fa.x; As[ra][ca + 1] = fa.y;
        As[ra][ca + 2] = fa.z; As[ra][ca + 3] = fa.w;
        float4 fb = *(const float4*)(Bw + (size_t)(k0 + rb) * N + nBase + cb);
        Bs[rb][cb + 0] = fb.x; Bs[rb][cb + 1] = fb.y;
        Bs[rb][cb + 2] = fb.z; Bs[rb][cb + 3] = fb.w;
        __syncthreads();
        #pragma unroll
        for (int kk = 0; kk < 16; kk++) {
            float a0 = As[ty4 + 0][kk], a1 = As[ty4 + 1][kk];
            float a2 = As[ty4 + 2][kk], a3 = As[ty4 + 3][kk];
            float b0 = Bs[kk][tx4 + 0], b1 = Bs[kk][tx4 + 1];
            float b2 = Bs[kk][tx4 + 2], b3 = Bs[kk][tx4 + 3];
            acc[0][0] += a0 * b0; acc[0][1] += a0 * b1; acc[0][2] += a0 * b2; acc[0][3] += a0 * b3;
            acc[1][0] += a1 * b0; acc[1][1] += a1 * b1; acc[1][2] += a1 * b2; acc[1][3] += a1 * b3;
            acc[2][0] += a2 * b0; acc[2][1] += a2 * b1; acc[2][2] += a2 * b2; acc[2][3] += a2 * b3;
            acc[3][0] += a3 * b0; acc[3][1] += a3 * b1; acc[3][2] += a3 * b2; acc[3][3] += a3 * b3;
        }
        __syncthreads();
    }
    #pragma unroll
    for (int i = 0; i < 4; i++) {
        int m = mBase + ty4 + i;
        #pragma unroll
        for (int j = 0; j < 4; j++) {
            int n = nBase + tx4 + j;
            C[(size_t)m * N + n] = acc[i][j] + bias[n];
        }
    }
}

__global__ __launch_bounds__(256) void attn_kernel(
    const float* __restrict__ qb, const float* __restrict__ kb, const float* __restrict__ vb,
    const int* __restrict__ mask, float* __restrict__ scores_out, float* __restrict__ ctx,
    int row_cut)
{
    __shared__ float qs[HDIM];
    __shared__ float sc[SEQ];
    __shared__ float red[4];
    __shared__ float part[4][HDIM];
    int tid = threadIdx.x;
    int q = blockIdx.x, h = blockIdx.y, b = blockIdx.z;
    bool wr = (b * HEADS + h) < row_cut;

    if (tid < HDIM)
        qs[tid] = qb[((size_t)(b * SEQ + q)) * HIDDEN + h * HDIM + tid];
    __syncthreads();

    const int* mrow = mask + ((size_t)(b * SEQ + q)) * SEQ;
    const float* kbase = kb + (size_t)b * SEQ * HIDDEN + h * HDIM;
    float* srow = scores_out + (((size_t)(b * HEADS + h)) * SEQ + q) * SEQ;

    float lmax = -3.0e38f;
    for (int j = tid; j < SEQ; j += 256) {
        const float4* kp = (const float4*)(kbase + (size_t)j * HIDDEN);
        float dot = 0.f;
        #pragma unroll
        for (int c = 0; c < 16; c++) {
            float4 u = kp[c];
            dot += qs[c * 4 + 0] * u.x + qs[c * 4 + 1] * u.y
                 + qs[c * 4 + 2] * u.z + qs[c * 4 + 3] * u.w;
        }
        float s = (mrow[j] == 0) ? NEGV : dot * 0.125f;
        sc[j] = s;
        if (wr) srow[j] = s;
        lmax = fmaxf(lmax, s);
    }
    #pragma unroll
    for (int o = 32; o > 0; o >>= 1) lmax = fmaxf(lmax, __shfl_xor(lmax, o, 64));
    __syncthreads();
    if ((tid & 63) == 0) red[tid >> 6] = lmax;
    __syncthreads();
    float m = fmaxf(fmaxf(red[0], red[1]), fmaxf(red[2], red[3]));

    float lsum = 0.f;
    for (int j = tid; j < SEQ; j += 256) {
        float e = __expf(sc[j] - m);
        sc[j] = e;
        lsum += e;
    }
    #pragma unroll
    for (int o = 32; o > 0; o >>= 1) lsum += __shfl_xor(lsum, o, 64);
    __syncthreads();
    if ((tid & 63) == 0) red[tid >> 6] = lsum;
    __syncthreads();
    float inv = 1.0f / (red[0] + red[1] + red[2] + red[3]);

    int d = tid & 63, chunk = tid >> 6;
    const float* vbase = vb + (size_t)b * SEQ * HIDDEN + h * HDIM + d;
    float acc = 0.f;
    int j0 = chunk * 512;
    for (int j = j0; j < j0 + 512; j++)
        acc += sc[j] * vbase[(size_t)j * HIDDEN];
    part[chunk][d] = acc;
    __syncthreads();
    if (tid < HDIM) {
        float r = (part[0][tid] + part[1][tid] + part[2][tid] + part[3][tid]) * inv;
        ctx[((size_t)(b * SEQ + q)) * HIDDEN + h * HDIM + tid] = r;
    }
}

__global__ __launch_bounds__(256) void ln_kernel(float* __restrict__ hbuf,
    const float* __restrict__ x, const float* __restrict__ g, const float* __restrict__ bb,
    float* __restrict__ out)
{
    __shared__ float red[4];
    int row = blockIdx.x, tid = threadIdx.x;
    size_t base = (size_t)row * HIDDEN + tid * 4;
    float4 fh = *(const float4*)(hbuf + base);
    float4 fx = *(const float4*)(x + base);
    float y0 = fh.x + fx.x, y1 = fh.y + fx.y, y2 = fh.z + fx.z, y3 = fh.w + fx.w;

    float s = y0 + y1 + y2 + y3;
    #pragma unroll
    for (int o = 32; o > 0; o >>= 1) s += __shfl_xor(s, o, 64);
    if ((tid & 63) == 0) red[tid >> 6] = s;
    __syncthreads();
    float mu = (red[0] + red[1] + red[2] + red[3]) * (1.f / 1024.f);

    float d0 = y0 - mu, d1 = y1 - mu, d2 = y2 - mu, d3 = y3 - mu;
    float sq = d0 * d0 + d1 * d1 + d2 * d2 + d3 * d3;
    #pragma unroll
    for (int o = 32; o > 0; o >>= 1) sq += __shfl_xor(sq, o, 64);
    __syncthreads();
    if ((tid & 63) == 0) red[tid >> 6] = sq;
    __syncthreads();
    float var = (red[0] + red[1] + red[2] + red[3]) * (1.f / 1024.f);
    float r = rsqrtf(var + 1e-12f);

    float4 fg = *(const float4*)(g + tid * 4);
    float4 fb = *(const float4*)(bb + tid * 4);
    float4 o4;
    o4.x = d0 * r * fg.x + fb.x;
    o4.y = d1 * r * fg.y + fb.y;
    o4.z = d2 * r * fg.z + fb.z;
    o4.w = d3 * r * fg.w + fb.w;
    *(float4*)(out + base) = o4;
}

__global__ __launch_bounds__(256) void score_fixup(const float* __restrict__ x,
    const float* __restrict__ Wq, const float* __restrict__ bq,
    const float* __restrict__ Wk, const float* __restrict__ bk,
    const int* __restrict__ mask, float* __restrict__ scores)
{
    __shared__ float As[64][17];
    __shared__ float Bs[16][65];
    __shared__ float qt[64][65];
    __shared__ float kt[64][65];
    const int b = 1;
    int h = 13 + blockIdx.z;
    int qBase = blockIdx.y * 64, kkBase = blockIdx.x * 64;
    int hcol = h * HDIM;
    int tid = threadIdx.x;
    int tx = tid & 15, ty = tid >> 4;
    int ty4 = ty * 4, tx4 = tx * 4;
    int idA = tid * 4;
    int ra = idA >> 4, ca = idA & 15;
    int rb = idA >> 6, cb = idA & 63;

    for (int pass = 0; pass < 2; pass++) {
        int rowBase = b * SEQ + (pass ? kkBase : qBase);
        const float* W = pass ? Wk : Wq;
        const float* bias = pass ? bk : bq;
        float acc[4][4] = {};
        for (int k0 = 0; k0 < HIDDEN; k0 += 16) {
            float4 fa = *(const float4*)(x + (size_t)(rowBase + ra) * HIDDEN + k0 + ca);
            As[ra][ca + 0] = fa.x; As[ra][ca + 1] = fa.y;
            As[ra][ca + 2] = fa.z; As[ra][ca + 3] = fa.w;
            float4 fb = *(const float4*)(W + (size_t)(k0 + rb) * HIDDEN + hcol + cb);
            Bs[rb][cb + 0] = fb.x; Bs[rb][cb + 1] = fb.y;
            Bs[rb][cb + 2] = fb.z; Bs[rb][cb + 3] = fb.w;
            __syncthreads();
            #pragma unroll
            for (int kk = 0; kk < 16; kk++) {
                float a0 = As[ty4 + 0][kk], a1 = As[ty4 + 1][kk];
                float a2 = As[ty4 + 2][kk], a3 = As[ty4 + 3][kk];
                float b0 = Bs[kk][tx4 + 0], b1 = Bs[kk][tx4 + 1];
                float b2 = Bs[kk][tx4 + 2], b3 = Bs[kk][tx4 + 3];
                acc[0][0] += a0 * b0; acc[0][1] += a0 * b1; acc[0][2] += a0 * b2; acc[0][3] += a0 * b3;
                acc[1][0] += a1 * b0; acc[1][1] += a1 * b1; acc[1][2] += a1 * b2; acc[1][3] += a1 * b3;
                acc[2][0] += a2 * b0; acc[2][1] += a2 * b1; acc[2][2] += a2 * b2; acc[2][3] += a2 * b3;
                acc[3][0] += a3 * b0; acc[3][1] += a3 * b1; acc[3][2] += a3 * b2; acc[3][3] += a3 * b3;
            }
            __syncthreads();
        }
        #pragma unroll
        for (int i = 0; i < 4; i++)
            #pragma unroll
            for (int j = 0; j < 4; j++) {
                float v = acc[i][j] + bias[hcol + tx4 + j];
                if (pass) kt[ty4 + i][tx4 + j] = v;
                else      qt[ty4 + i][tx4 + j] = v;
            }
        __syncthreads();
    }

    float s[4][4] = {};
    for (int d = 0; d < HDIM; d++) {
        float qv0 = qt[ty4 + 0][d], qv1 = qt[ty4 + 1][d];
        float qv2 = qt[ty4 + 2][d], qv3 = qt[ty4 + 3][d];
        float kv0 = kt[tx4 + 0][d], kv1 = kt[tx4 + 1][d];
        float kv2 = kt[tx4 + 2][d], kv3 = kt[tx4 + 3][d];
        s[0][0] += qv0 * kv0; s[0][1] += qv0 * kv1; s[0][2] += qv0 * kv2; s[0][3] += qv0 * kv3;
        s[1][0] += qv1 * kv0; s[1][1] += qv1 * kv1; s[1][2] += qv1 * kv2; s[1][3] += qv1 * kv3;
        s[2][0] += qv2 * kv0; s[2][1] += qv2 * kv1; s[2][2] += qv2 * kv2; s[2][3] += qv2 * kv3;
        s[3][0] += qv3 * kv0; s[3][1] += qv3 * kv1; s[3][2] += qv3 * kv2; s[3][3] += qv3 * kv3;
    }
    #pragma unroll
    for (int i = 0; i < 4; i++) {
        int q = qBase + ty4 + i;
        const int* mrow = mask + ((size_t)(b * SEQ + q)) * SEQ;
        float* srow = scores + (((size_t)(b * HEADS + h)) * SEQ + q) * SEQ;
        #pragma unroll
        for (int j = 0; j < 4; j++) {
            int kk = kkBase + tx4 + j;
            srow[kk] = (mrow[kk] == 0) ? NEGV : s[i][j] * 0.125f;
        }
    }
}

extern "C" void kernel_launch(void* const* d_in, const int* in_sizes, int n_in,
                              void* d_out, int out_size, void* d_ws, size_t ws_size,
                              hipStream_t stream)
{
    const float* x   = (const float*)d_in[0];
    const int*   msk = (const int*)d_in[1];
    const float* Wq  = (const float*)d_in[2];
    const float* bq  = (const float*)d_in[3];
    const float* Wk  = (const float*)d_in[4];
    const float* bk  = (const float*)d_in[5];
    const float* Wv  = (const float*)d_in[6];
    const float* bv  = (const float*)d_in[7];
    const float* Wo  = (const float*)d_in[8];
    const float* bo  = (const float*)d_in[9];
    const float* lng = (const float*)d_in[10];
    const float* lnb = (const float*)d_in[11];

    float* out0   = (float*)d_out;                 // chunk 0: [B*S, HIDDEN]
    float* scores = out0 + (size_t)TOK;            // chunk 1: [B,H,S,S]

    const size_t need = (size_t)3 * TOK * sizeof(float);   // 48 MiB: K/V/ctx splits
    const bool use_ws = (d_ws != nullptr) && (ws_size >= need);

    const int M = BATCH * SEQ;

    if (use_ws) {
        // ws: K/V/ctx splits (6 x 8 MB = 48 MiB exact).
        unsigned short* Khi = (unsigned short*)d_ws;
        unsigned short* Klo = Khi + (size_t)TOK;
        unsigned short* Vhi = Klo + (size_t)TOK;
        unsigned short* Vlo = Vhi + (size_t)TOK;
        unsigned short* Chi = Vlo + (size_t)TOK;
        unsigned short* Clo = Chi + (size_t)TOK;
        // out0: Q split (16 MB exact; dead before Wo GEMM writes out0).
        unsigned short* Qhi = (unsigned short*)out0;
        unsigned short* Qlo = Qhi + (size_t)TOK;
        // scores region: pre-attention scratch (x split + W^T splits, ~29 MB of 537 MB).
        unsigned short* Xhi  = (unsigned short*)scores;
        unsigned short* Xlo  = Xhi + (size_t)TOK;
        unsigned short* WTqh = Xlo + (size_t)TOK;
        unsigned short* WTql = WTqh + (size_t)HH;
        unsigned short* WTkh = WTql + (size_t)HH;
        unsigned short* WTkl = WTkh + (size_t)HH;
        unsigned short* WTvh = WTkl + (size_t)HH;
        unsigned short* WTvl = WTvh + (size_t)HH;
        // Wo^T split: carved from dead K region of ws AFTER attention (4 MB < 8 MB).
        unsigned short* WToh = Khi;
        unsigned short* WTol = Khi + (size_t)HH;

        split_rows<<<TOK / (256 * 8), 256, 0, stream>>>(x, Xhi, Xlo);
        dim3 gt(16, 16);
        split_T<<<gt, 256, 0, stream>>>(Wq, WTqh, WTql);
        split_T<<<gt, 256, 0, stream>>>(Wk, WTkh, WTkl);
        split_T<<<gt, 256, 0, stream>>>(Wv, WTvh, WTvl);

        dim3 gg(HIDDEN / 128, M / 128);   // (8, 32) = 256 blocks
        gemm_ps<1><<<gg, 512, 0, stream>>>(Xhi, Xlo, WTqh, WTql, bq,
                                           nullptr, Qhi, Qlo, M, HIDDEN, HIDDEN);
        gemm_ps<1><<<gg, 512, 0, stream>>>(Xhi, Xlo, WTkh, WTkl, bk,
                                           nullptr, Khi, Klo, M, HIDDEN, HIDDEN);
        gemm_ps<1><<<gg, 512, 0, stream>>>(Xhi, Xlo, WTvh, WTvl, bv,
                                           nullptr, Vhi, Vlo, M, HIDDEN, HIDDEN);
        attn_mfma<<<dim3(SEQ / 128, HEADS, BATCH), 256, 0, stream>>>(
            Qhi, Qlo, Khi, Klo, Vhi, Vlo, msk, scores, Chi, Clo);
        split_T<<<gt, 256, 0, stream>>>(Wo, WToh, WTol);
        gemm_ps<0><<<gg, 512, 0, stream>>>(Chi, Clo, WToh, WTol, bo,
                                           out0, nullptr, nullptr, M, HIDDEN, HIDDEN);
        ln_kernel<<<M, 256, 0, stream>>>(out0, x, lng, lnb, out0);
    } else {
        // fp32 fallback (scratch carved from score tail + fixup)
        float* Ks = scores + (SC_N - (size_t)3 * TOK);
        float* Vs = Ks + (size_t)TOK;
        float* Cs = Vs + (size_t)TOK;
        float* Qs = out0;
        dim3 gg(HIDDEN / 64, M / 64);
        gemm_bias<<<gg, 256, 0, stream>>>(x, Wq, bq, Qs, M, HIDDEN, HIDDEN);
        gemm_bias<<<gg, 256, 0, stream>>>(x, Wk, bk, Ks, M, HIDDEN, HIDDEN);
        gemm_bias<<<gg, 256, 0, stream>>>(x, Wv, bv, Vs, M, HIDDEN, HIDDEN);
        attn_kernel<<<dim3(SEQ, HEADS, BATCH), 256, 0, stream>>>(Qs, Ks, Vs, msk, scores, Cs, ROW_CUT);
        gemm_bias<<<gg, 256, 0, stream>>>(Cs, Wo, bo, out0, M, HIDDEN, HIDDEN);
        ln_kernel<<<M, 256, 0, stream>>>(out0, x, lng, lnb, out0);
        score_fixup<<<dim3(SEQ / 64, SEQ / 64, 3), 256, 0, stream>>>(x, Wq, bq, Wk, bk, msk, scores);
    }
}

// Round 5
// 935.640 us; speedup vs baseline: 1.4817x; 1.4817x over previous
//
#include <hip/hip_runtime.h>
#include <math.h>

#define HIDDEN 1024
#define HEADS 16
#define HDIM 64
#define BATCH 2
#define SEQ 2048
#define NEGV -1.0e9f
#define TOK (BATCH * SEQ * HIDDEN)            // 4,194,304
#define HH (HIDDEN * HIDDEN)                  // 1,048,576
#define SC_N ((size_t)BATCH * HEADS * SEQ * SEQ)  // 134,217,728
#define ROW_CUT 29
#define PIT 72   // attn LDS pitch (144B rows)

typedef __bf16 bf16x8 __attribute__((ext_vector_type(8)));
typedef float f32x4 __attribute__((ext_vector_type(4)));

__device__ __forceinline__ unsigned short f2bf(float f) {
    union { float f; unsigned u; } v; v.f = f;
    unsigned r = (v.u + 0x7fffu + ((v.u >> 16) & 1u)) >> 16;
    return (unsigned short)r;
}
__device__ __forceinline__ float bf2f(unsigned short h) {
    union { unsigned u; float f; } v; v.u = ((unsigned)h) << 16;
    return v.f;
}
__device__ __forceinline__ void split_bf(float v, unsigned short& h, unsigned short& l) {
    h = f2bf(v);
    l = f2bf(v - bf2f(h));
}
__device__ __forceinline__ bf16x8 ld_frag(const unsigned short* p) {
    union { uint4 u; bf16x8 v; } t;
    t.u = *(const uint4*)p;
    return t.v;
}
// async global->LDS, 16B per lane; LDS dest = wave-uniform base + lane*16
__device__ __forceinline__ void gl2lds16(const unsigned short* g, unsigned short* l) {
    __builtin_amdgcn_global_load_lds(
        (const __attribute__((address_space(1))) void*)g,
        (__attribute__((address_space(3))) void*)l, 16, 0, 0);
}

// ---------------- split fp32 array -> (hi, lo) bf16, same layout. 8/thread.
__global__ __launch_bounds__(256) void split_rows(const float* __restrict__ in,
    unsigned short* __restrict__ hi, unsigned short* __restrict__ lo)
{
    size_t i = ((size_t)blockIdx.x * 256 + threadIdx.x) * 8;
    float4 f0 = *(const float4*)(in + i);
    float4 f1 = *(const float4*)(in + i + 4);
    union { uint4 u; unsigned short s[8]; } H, L;
    split_bf(f0.x, H.s[0], L.s[0]); split_bf(f0.y, H.s[1], L.s[1]);
    split_bf(f0.z, H.s[2], L.s[2]); split_bf(f0.w, H.s[3], L.s[3]);
    split_bf(f1.x, H.s[4], L.s[4]); split_bf(f1.y, H.s[5], L.s[5]);
    split_bf(f1.z, H.s[6], L.s[6]); split_bf(f1.w, H.s[7], L.s[7]);
    *(uint4*)(hi + i) = H.u;
    *(uint4*)(lo + i) = L.u;
}

// ---------------- split + transpose: W[K][N] fp32 -> WT(hi,lo)[N][K] bf16. 64x64 tiles.
__global__ __launch_bounds__(256) void split_T(const float* __restrict__ W,
    unsigned short* __restrict__ Thi, unsigned short* __restrict__ Tlo)
{
    __shared__ float Ts[64][65];
    int n0 = blockIdx.x * 64, k0 = blockIdx.y * 64;
    int tid = threadIdx.x;
    int r = tid >> 4, c4 = (tid & 15) * 4;
    #pragma unroll
    for (int i = 0; i < 4; i++) {
        int rr = r + i * 16;
        float4 f = *(const float4*)&W[(size_t)(k0 + rr) * HIDDEN + n0 + c4];
        Ts[rr][c4 + 0] = f.x; Ts[rr][c4 + 1] = f.y;
        Ts[rr][c4 + 2] = f.z; Ts[rr][c4 + 3] = f.w;
    }
    __syncthreads();
    int rp = tid >> 3, g = tid & 7;
    #pragma unroll
    for (int i = 0; i < 2; i++) {
        int nr = rp + i * 32;
        union { uint4 u; unsigned short s[8]; } Hh, Ll;
        #pragma unroll
        for (int d = 0; d < 8; d++)
            split_bf(Ts[g * 8 + d][nr], Hh.s[d], Ll.s[d]);
        size_t o = (size_t)(n0 + nr) * HIDDEN + k0 + g * 8;
        *(uint4*)&Thi[o] = Hh.u;
        *(uint4*)&Tlo[o] = Ll.u;
    }
}

// ---------------- presplit MFMA GEMM with global_load_lds staging.
// A (Ahi,Alo)[M][K]; B (BThi,BTlo)[N][K] pre-transposed. BM=BN=128, BK=64,
// 512 thr = 8 waves (2M x 4N), wave tile 64x32. LDS linear [128][64] (no pad);
// XOR-swizzle on READ, inverse-swizzle on GLOBAL SOURCE (rule #21).
// FUSED=1: N=3*HIDDEN, split-out to (o0,o1,o2) selected by n>>10 with bias b0/b1/b2.
// FUSED=0: fp32 C + bias b0.
template<int FUSED>
__global__ __launch_bounds__(512) void gemm_ps(
    const unsigned short* __restrict__ Ahi, const unsigned short* __restrict__ Alo,
    const unsigned short* __restrict__ BThi, const unsigned short* __restrict__ BTlo,
    const float* __restrict__ b0, const float* __restrict__ b1, const float* __restrict__ b2,
    float* __restrict__ C,
    unsigned short* __restrict__ o0h, unsigned short* __restrict__ o0l,
    unsigned short* __restrict__ o1h, unsigned short* __restrict__ o1l,
    unsigned short* __restrict__ o2h, unsigned short* __restrict__ o2l,
    int M)
{
    __shared__ unsigned short Ah[128][64], Al[128][64];
    __shared__ unsigned short Bh[128][64], Bl[128][64];
    const int K = HIDDEN;
    int tid = threadIdx.x;
    int lane = tid & 63, wv = tid >> 6;
    int wm = wv >> 2, wn = wv & 3;
    int l15 = lane & 15, l4 = lane >> 4;
    int mBase = blockIdx.y * 128, nBase = blockIdx.x * 128;
    int srow = lane >> 3, schk = lane & 7;   // 8 rows x 8 chunks per wave-load

    f32x4 acc[4][2] = {};

    for (int kt = 0; kt < K; kt += 64) {
        // ---- stage: each wave fills rows [wv*16, wv*16+16) of all 4 arrays
        #pragma unroll
        for (int i = 0; i < 2; i++) {
            int r0 = wv * 16 + i * 8;
            int row = r0 + srow;
            int co = (schk * 8) ^ ((row & 7) << 3);   // inverse-swizzled source (ushort units)
            gl2lds16(&Ahi[(size_t)(mBase + row) * K + kt + co], &Ah[r0][0]);
            gl2lds16(&Alo[(size_t)(mBase + row) * K + kt + co], &Al[r0][0]);
            gl2lds16(&BThi[(size_t)(nBase + row) * K + kt + co], &Bh[r0][0]);
            gl2lds16(&BTlo[(size_t)(nBase + row) * K + kt + co], &Bl[r0][0]);
        }
        __syncthreads();   // compiler drains vmcnt(0) before barrier

        #pragma unroll
        for (int ks = 0; ks < 2; ks++) {
            int ko = ks * 32 + l4 * 8;
            bf16x8 aH[4], aL[4], bH[2], bL[2];
            #pragma unroll
            for (int ti = 0; ti < 4; ti++) {
                int ar = wm * 64 + ti * 16 + l15;
                int ac = ko ^ ((ar & 7) << 3);
                aH[ti] = ld_frag(&Ah[ar][ac]);
                aL[ti] = ld_frag(&Al[ar][ac]);
            }
            #pragma unroll
            for (int tj = 0; tj < 2; tj++) {
                int br = wn * 32 + tj * 16 + l15;
                int bc = ko ^ ((br & 7) << 3);
                bH[tj] = ld_frag(&Bh[br][bc]);
                bL[tj] = ld_frag(&Bl[br][bc]);
            }
            #pragma unroll
            for (int ti = 0; ti < 4; ti++)
                #pragma unroll
                for (int tj = 0; tj < 2; tj++) {
                    acc[ti][tj] = __builtin_amdgcn_mfma_f32_16x16x32_bf16(aH[ti], bH[tj], acc[ti][tj], 0, 0, 0);
                    acc[ti][tj] = __builtin_amdgcn_mfma_f32_16x16x32_bf16(aH[ti], bL[tj], acc[ti][tj], 0, 0, 0);
                    acc[ti][tj] = __builtin_amdgcn_mfma_f32_16x16x32_bf16(aL[ti], bH[tj], acc[ti][tj], 0, 0, 0);
                }
        }
        __syncthreads();
    }

    // ---- epilogue
    const unsigned short* dummy = nullptr; (void)dummy;
    int t = nBase >> 10;                       // tensor select (uniform per block)
    unsigned short* Oh = FUSED ? (t == 0 ? o0h : t == 1 ? o1h : o2h) : nullptr;
    unsigned short* Ol = FUSED ? (t == 0 ? o0l : t == 1 ? o1l : o2l) : nullptr;
    const float* bias = FUSED ? (t == 0 ? b0 : t == 1 ? b1 : b2) : b0;
    int nOff = FUSED ? (nBase & 1023) : nBase;

    #pragma unroll
    for (int ti = 0; ti < 4; ti++) {
        #pragma unroll
        for (int tj = 0; tj < 2; tj++) {
            int m0 = mBase + wm * 64 + ti * 16 + l4 * 4;
            int nc = nOff + wn * 32 + tj * 16 + l15;
            float bv = bias[nc];
            #pragma unroll
            for (int rg = 0; rg < 4; rg++) {
                float v = acc[ti][tj][rg] + bv;
                if (FUSED) {
                    unsigned short hh, ll;
                    split_bf(v, hh, ll);
                    Oh[(size_t)(m0 + rg) * HIDDEN + nc] = hh;
                    Ol[(size_t)(m0 + rg) * HIDDEN + nc] = ll;
                } else {
                    C[(size_t)(m0 + rg) * HIDDEN + nc] = v;
                }
            }
        }
    }
}

// ---------------- MFMA attention (round-3 structure, QBLK=64) + verified V^T XOR swizzle.
// Block = (64-q-tile, h, b), 4 waves; wave w owns q rows [w*16, w*16+16).
__global__ __launch_bounds__(256) void attn_mfma(
    const unsigned short* __restrict__ Qhi, const unsigned short* __restrict__ Qlo,
    const unsigned short* __restrict__ Khi, const unsigned short* __restrict__ Klo,
    const unsigned short* __restrict__ Vhi, const unsigned short* __restrict__ Vlo,
    const int* __restrict__ mask, float* __restrict__ scores_out,
    unsigned short* __restrict__ Chi, unsigned short* __restrict__ Clo)
{
    __shared__ unsigned short Kh[64][PIT], Kl[64][PIT];
    __shared__ unsigned short Th[64][PIT], Tl[64][PIT];   // V^T [d][k], k XOR-block-swizzled
    __shared__ unsigned short Ph[4][16][PIT], Pl[4][16][PIT];

    int tid = threadIdx.x;
    int lane = tid & 63, w = tid >> 6;
    int l15 = lane & 15, l4 = lane >> 4;
    int qBase = blockIdx.x * 64;
    int h = blockIdx.y, b = blockIdx.z;

    size_t qofs = (size_t)(b * SEQ + qBase + w * 16 + l15) * HIDDEN + h * HDIM;
    bf16x8 qh0 = ld_frag(&Qhi[qofs + l4 * 8]);
    bf16x8 qh1 = ld_frag(&Qhi[qofs + 32 + l4 * 8]);
    bf16x8 ql0 = ld_frag(&Qlo[qofs + l4 * 8]);
    bf16x8 ql1 = ld_frag(&Qlo[qofs + 32 + l4 * 8]);

    f32x4 cacc[4] = {};
    float mrow[4] = {-3.0e38f, -3.0e38f, -3.0e38f, -3.0e38f};
    float rsum[4] = {0.f, 0.f, 0.f, 0.f};

    for (int kt = 0; kt < SEQ; kt += 64) {
        // ---- stage K rows + V^T (swizzled columns, verified in round 4)
        {
            int r = tid >> 3, g = tid & 7;
            #pragma unroll
            for (int i = 0; i < 2; i++) {
                int rr = r + i * 32;
                size_t tok = (size_t)(b * SEQ + kt + rr) * HIDDEN + h * HDIM + g * 8;
                *(uint4*)&Kh[rr][g * 8] = *(const uint4*)&Khi[tok];
                *(uint4*)&Kl[rr][g * 8] = *(const uint4*)&Klo[tok];
                union { uint4 u; unsigned short s[8]; } vh, vl;
                vh.u = *(const uint4*)&Vhi[tok];
                vl.u = *(const uint4*)&Vlo[tok];
                int cbs = ((((rr >> 3) ^ g) & 7) << 3) + (rr & 7);
                #pragma unroll
                for (int dd = 0; dd < 8; dd++) {
                    Th[g * 8 + dd][cbs] = vh.s[dd];
                    Tl[g * 8 + dd][cbs] = vl.s[dd];
                }
            }
        }
        __syncthreads();

        // ---- S strip = Q K^T (16 x 64)
        f32x4 sacc[4] = {};
        #pragma unroll
        for (int ks = 0; ks < 64; ks += 32) {
            int ko = ks + l4 * 8;
            bf16x8 qH = ks ? qh1 : qh0;
            bf16x8 qL = ks ? ql1 : ql0;
            #pragma unroll
            for (int j = 0; j < 4; j++) {
                bf16x8 kH = ld_frag(&Kh[j * 16 + l15][ko]);
                bf16x8 kL = ld_frag(&Kl[j * 16 + l15][ko]);
                sacc[j] = __builtin_amdgcn_mfma_f32_16x16x32_bf16(qH, kH, sacc[j], 0, 0, 0);
                sacc[j] = __builtin_amdgcn_mfma_f32_16x16x32_bf16(qH, kL, sacc[j], 0, 0, 0);
                sacc[j] = __builtin_amdgcn_mfma_f32_16x16x32_bf16(qL, kH, sacc[j], 0, 0, 0);
            }
        }

        // ---- mask + scale + score write
        float sv[4][4];
        #pragma unroll
        for (int j = 0; j < 4; j++) {
            #pragma unroll
            for (int rg = 0; rg < 4; rg++) {
                int qrow = qBase + w * 16 + l4 * 4 + rg;
                int kc = kt + j * 16 + l15;
                int mval = mask[(size_t)(b * SEQ + qrow) * SEQ + kc];
                float s = (mval == 0) ? NEGV : sacc[j][rg] * 0.125f;
                scores_out[((size_t)(b * HEADS + h) * SEQ + qrow) * SEQ + kc] = s;
                sv[j][rg] = s;
            }
        }

        // ---- online softmax per row
        #pragma unroll
        for (int rg = 0; rg < 4; rg++) {
            float tmax = fmaxf(fmaxf(sv[0][rg], sv[1][rg]), fmaxf(sv[2][rg], sv[3][rg]));
            #pragma unroll
            for (int o = 1; o < 16; o <<= 1)
                tmax = fmaxf(tmax, __shfl_xor(tmax, o, 64));
            float mn = fmaxf(mrow[rg], tmax);
            float fac = __expf(mrow[rg] - mn);
            mrow[rg] = mn;
            float ts = 0.f;
            #pragma unroll
            for (int j = 0; j < 4; j++) {
                float e = __expf(sv[j][rg] - mn);
                unsigned short ph, pl;
                split_bf(e, ph, pl);
                Ph[w][l4 * 4 + rg][j * 16 + l15] = ph;
                Pl[w][l4 * 4 + rg][j * 16 + l15] = pl;
                ts += e;
            }
            #pragma unroll
            for (int o = 1; o < 16; o <<= 1)
                ts += __shfl_xor(ts, o, 64);
            rsum[rg] = rsum[rg] * fac + ts;
            cacc[0][rg] *= fac; cacc[1][rg] *= fac;
            cacc[2][rg] *= fac; cacc[3][rg] *= fac;
        }

        // ---- ctx += P V (swizzled V read)
        #pragma unroll
        for (int ks = 0; ks < 64; ks += 32) {
            int ko = ks + l4 * 8;
            bf16x8 pH = ld_frag(&Ph[w][l15][ko]);
            bf16x8 pL = ld_frag(&Pl[w][l15][ko]);
            #pragma unroll
            for (int j = 0; j < 4; j++) {
                int drow = j * 16 + l15;
                int pb = (((ko >> 3) ^ (drow >> 3)) & 7) << 3;
                bf16x8 vH = ld_frag(&Th[drow][pb]);
                bf16x8 vL = ld_frag(&Tl[drow][pb]);
                cacc[j] = __builtin_amdgcn_mfma_f32_16x16x32_bf16(pH, vH, cacc[j], 0, 0, 0);
                cacc[j] = __builtin_amdgcn_mfma_f32_16x16x32_bf16(pH, vL, cacc[j], 0, 0, 0);
                cacc[j] = __builtin_amdgcn_mfma_f32_16x16x32_bf16(pL, vH, cacc[j], 0, 0, 0);
            }
        }
        __syncthreads();
    }

    // ---- epilogue: ctx split-write for Wo GEMM
    #pragma unroll
    for (int rg = 0; rg < 4; rg++) {
        float inv = 1.0f / rsum[rg];
        int qrow = qBase + w * 16 + l4 * 4 + rg;
        size_t obase = (size_t)(b * SEQ + qrow) * HIDDEN + h * HDIM;
        #pragma unroll
        for (int j = 0; j < 4; j++) {
            float v = cacc[j][rg] * inv;
            unsigned short hh, ll;
            split_bf(v, hh, ll);
            Chi[obase + j * 16 + l15] = hh;
            Clo[obase + j * 16 + l15] = ll;
        }
    }
}

// ================= fp32 fallback path (used only if ws too small) =================
__global__ __launch_bounds__(256) void gemm_bias(const float* __restrict__ A,
    const float* __restrict__ Bw, const float* __restrict__ bias,
    float* __restrict__ C, int M, int N, int K)
{
    __shared__ float As[64][17];
    __shared__ float Bs[16][65];
    int tid = threadIdx.x;
    int tx = tid & 15, ty = tid >> 4;
    int mBase = blockIdx.y * 64, nBase = blockIdx.x * 64;
    float acc[4][4] = {};
    int idA = tid * 4;
    int ra = idA >> 4, ca = idA & 15;
    int rb = idA >> 6, cb = idA & 63;
    int ty4 = ty * 4, tx4 = tx * 4;
    for (int k0 = 0; k0 < K; k0 += 16) {
        float4 fa = *(const float4*)(A + (size_t)(mBase + ra) * K + k0 + ca);
        As[ra][ca + 0] = fa.x; As[ra][ca + 1] = fa.y;
        As[ra][ca + 2] = fa.z; As[ra][ca + 3] = fa.w;
        float4 fb = *(const float4*)(Bw + (size_t)(k0 + rb) * N + nBase + cb);
        Bs[rb][cb + 0] = fb.x; Bs[rb][cb + 1] = fb.y;
        Bs[rb][cb + 2] = fb.z; Bs[rb][cb + 3] = fb.w;
        __syncthreads();
        #pragma unroll
        for (int kk = 0; kk < 16; kk++) {
            float a0 = As[ty4 + 0][kk], a1 = As[ty4 + 1][kk];
            float a2 = As[ty4 + 2][kk], a3 = As[ty4 + 3][kk];
            float b0 = Bs[kk][tx4 + 0], b1 = Bs[kk][tx4 + 1];
            float b2 = Bs[kk][tx4 + 2], b3 = Bs[kk][tx4 + 3];
            acc[0][0] += a0 * b0; acc[0][1] += a0 * b1; acc[0][2] += a0 * b2; acc[0][3] += a0 * b3;
            acc[1][0] += a1 * b0; acc[1][1] += a1 * b1; acc[1][2] += a1 * b2; acc[1][3] += a1 * b3;
            acc[2][0] += a2 * b0; acc[2][1] += a2 * b1; acc[2][2] += a2 * b2; acc[2][3] += a2 * b3;
            acc[3][0] += a3 * b0; acc[3][1] += a3 * b1; acc[3][2] += a3 * b2; acc[3][3] += a3 * b3;
        }
        __syncthreads();
    }
    #pragma unroll
    for (int i = 0; i < 4; i++) {
        int m = mBase + ty4 + i;
        #pragma unroll
        for (int j = 0; j < 4; j++) {
            int n = nBase + tx4 + j;
            C[(size_t)m * N + n] = acc[i][j] + bias[n];
        }
    }
}

__global__ __launch_bounds__(256) void attn_kernel(
    const float* __restrict__ qb, const float* __restrict__ kb, const float* __restrict__ vb,
    const int* __restrict__ mask, float* __restrict__ scores_out, float* __restrict__ ctx,
    int row_cut)
{
    __shared__ float qs[HDIM];
    __shared__ float sc[SEQ];
    __shared__ float red[4];
    __shared__ float part[4][HDIM];
    int tid = threadIdx.x;
    int q = blockIdx.x, h = blockIdx.y, b = blockIdx.z;
    bool wr = (b * HEADS + h) < row_cut;

    if (tid < HDIM)
        qs[tid] = qb[((size_t)(b * SEQ + q)) * HIDDEN + h * HDIM + tid];
    __syncthreads();

    const int* mrow = mask + ((size_t)(b * SEQ + q)) * SEQ;
    const float* kbase = kb + (size_t)b * SEQ * HIDDEN + h * HDIM;
    float* srow = scores_out + (((size_t)(b * HEADS + h)) * SEQ + q) * SEQ;

    float lmax = -3.0e38f;
    for (int j = tid; j < SEQ; j += 256) {
        const float4* kp = (const float4*)(kbase + (size_t)j * HIDDEN);
        float dot = 0.f;
        #pragma unroll
        for (int c = 0; c < 16; c++) {
            float4 u = kp[c];
            dot += qs[c * 4 + 0] * u.x + qs[c * 4 + 1] * u.y
                 + qs[c * 4 + 2] * u.z + qs[c * 4 + 3] * u.w;
        }
        float s = (mrow[j] == 0) ? NEGV : dot * 0.125f;
        sc[j] = s;
        if (wr) srow[j] = s;
        lmax = fmaxf(lmax, s);
    }
    #pragma unroll
    for (int o = 32; o > 0; o >>= 1) lmax = fmaxf(lmax, __shfl_xor(lmax, o, 64));
    __syncthreads();
    if ((tid & 63) == 0) red[tid >> 6] = lmax;
    __syncthreads();
    float m = fmaxf(fmaxf(red[0], red[1]), fmaxf(red[2], red[3]));

    float lsum = 0.f;
    for (int j = tid; j < SEQ; j += 256) {
        float e = __expf(sc[j] - m);
        sc[j] = e;
        lsum += e;
    }
    #pragma unroll
    for (int o = 32; o > 0; o >>= 1) lsum += __shfl_xor(lsum, o, 64);
    __syncthreads();
    if ((tid & 63) == 0) red[tid >> 6] = lsum;
    __syncthreads();
    float inv = 1.0f / (red[0] + red[1] + red[2] + red[3]);

    int d = tid & 63, chunk = tid >> 6;
    const float* vbase = vb + (size_t)b * SEQ * HIDDEN + h * HDIM + d;
    float acc = 0.f;
    int j0 = chunk * 512;
    for (int j = j0; j < j0 + 512; j++)
        acc += sc[j] * vbase[(size_t)j * HIDDEN];
    part[chunk][d] = acc;
    __syncthreads();
    if (tid < HDIM) {
        float r = (part[0][tid] + part[1][tid] + part[2][tid] + part[3][tid]) * inv;
        ctx[((size_t)(b * SEQ + q)) * HIDDEN + h * HDIM + tid] = r;
    }
}

__global__ __launch_bounds__(256) void ln_kernel(float* __restrict__ hbuf,
    const float* __restrict__ x, const float* __restrict__ g, const float* __restrict__ bb,
    float* __restrict__ out)
{
    __shared__ float red[4];
    int row = blockIdx.x, tid = threadIdx.x;
    size_t base = (size_t)row * HIDDEN + tid * 4;
    float4 fh = *(const float4*)(hbuf + base);
    float4 fx = *(const float4*)(x + base);
    float y0 = fh.x + fx.x, y1 = fh.y + fx.y, y2 = fh.z + fx.z, y3 = fh.w + fx.w;

    float s = y0 + y1 + y2 + y3;
    #pragma unroll
    for (int o = 32; o > 0; o >>= 1) s += __shfl_xor(s, o, 64);
    if ((tid & 63) == 0) red[tid >> 6] = s;
    __syncthreads();
    float mu = (red[0] + red[1] + red[2] + red[3]) * (1.f / 1024.f);

    float d0 = y0 - mu, d1 = y1 - mu, d2 = y2 - mu, d3 = y3 - mu;
    float sq = d0 * d0 + d1 * d1 + d2 * d2 + d3 * d3;
    #pragma unroll
    for (int o = 32; o > 0; o >>= 1) sq += __shfl_xor(sq, o, 64);
    __syncthreads();
    if ((tid & 63) == 0) red[tid >> 6] = sq;
    __syncthreads();
    float var = (red[0] + red[1] + red[2] + red[3]) * (1.f / 1024.f);
    float r = rsqrtf(var + 1e-12f);

    float4 fg = *(const float4*)(g + tid * 4);
    float4 fb = *(const float4*)(bb + tid * 4);
    float4 o4;
    o4.x = d0 * r * fg.x + fb.x;
    o4.y = d1 * r * fg.y + fb.y;
    o4.z = d2 * r * fg.z + fb.z;
    o4.w = d3 * r * fg.w + fb.w;
    *(float4*)(out + base) = o4;
}

__global__ __launch_bounds__(256) void score_fixup(const float* __restrict__ x,
    const float* __restrict__ Wq, const float* __restrict__ bq,
    const float* __restrict__ Wk, const float* __restrict__ bk,
    const int* __restrict__ mask, float* __restrict__ scores)
{
    __shared__ float As[64][17];
    __shared__ float Bs[16][65];
    __shared__ float qt[64][65];
    __shared__ float kt[64][65];
    const int b = 1;
    int h = 13 + blockIdx.z;
    int qBase = blockIdx.y * 64, kkBase = blockIdx.x * 64;
    int hcol = h * HDIM;
    int tid = threadIdx.x;
    int tx = tid & 15, ty = tid >> 4;
    int ty4 = ty * 4, tx4 = tx * 4;
    int idA = tid * 4;
    int ra = idA >> 4, ca = idA & 15;
    int rb = idA >> 6, cb = idA & 63;

    for (int pass = 0; pass < 2; pass++) {
        int rowBase = b * SEQ + (pass ? kkBase : qBase);
        const float* W = pass ? Wk : Wq;
        const float* bias = pass ? bk : bq;
        float acc[4][4] = {};
        for (int k0 = 0; k0 < HIDDEN; k0 += 16) {
            float4 fa = *(const float4*)(x + (size_t)(rowBase + ra) * HIDDEN + k0 + ca);
            As[ra][ca + 0] = fa.x; As[ra][ca + 1] = fa.y;
            As[ra][ca + 2] = fa.z; As[ra][ca + 3] = fa.w;
            float4 fb = *(const float4*)(W + (size_t)(k0 + rb) * HIDDEN + hcol + cb);
            Bs[rb][cb + 0] = fb.x; Bs[rb][cb + 1] = fb.y;
            Bs[rb][cb + 2] = fb.z; Bs[rb][cb + 3] = fb.w;
            __syncthreads();
            #pragma unroll
            for (int kk = 0; kk < 16; kk++) {
                float a0 = As[ty4 + 0][kk], a1 = As[ty4 + 1][kk];
                float a2 = As[ty4 + 2][kk], a3 = As[ty4 + 3][kk];
                float b0 = Bs[kk][tx4 + 0], b1 = Bs[kk][tx4 + 1];
                float b2 = Bs[kk][tx4 + 2], b3 = Bs[kk][tx4 + 3];
                acc[0][0] += a0 * b0; acc[0][1] += a0 * b1; acc[0][2] += a0 * b2; acc[0][3] += a0 * b3;
                acc[1][0] += a1 * b0; acc[1][1] += a1 * b1; acc[1][2] += a1 * b2; acc[1][3] += a1 * b3;
                acc[2][0] += a2 * b0; acc[2][1] += a2 * b1; acc[2][2] += a2 * b2; acc[2][3] += a2 * b3;
                acc[3][0] += a3 * b0; acc[3][1] += a3 * b1; acc[3][2] += a3 * b2; acc[3][3] += a3 * b3;
            }
            __syncthreads();
        }
        #pragma unroll
        for (int i = 0; i < 4; i++)
            #pragma unroll
            for (int j = 0; j < 4; j++) {
                float v = acc[i][j] + bias[hcol + tx4 + j];
                if (pass) kt[ty4 + i][tx4 + j] = v;
                else      qt[ty4 + i][tx4 + j] = v;
            }
        __syncthreads();
    }

    float s[4][4] = {};
    for (int d = 0; d < HDIM; d++) {
        float qv0 = qt[ty4 + 0][d], qv1 = qt[ty4 + 1][d];
        float qv2 = qt[ty4 + 2][d], qv3 = qt[ty4 + 3][d];
        float kv0 = kt[tx4 + 0][d], kv1 = kt[tx4 + 1][d];
        float kv2 = kt[tx4 + 2][d], kv3 = kt[tx4 + 3][d];
        s[0][0] += qv0 * kv0; s[0][1] += qv0 * kv1; s[0][2] += qv0 * kv2; s[0][3] += qv0 * kv3;
        s[1][0] += qv1 * kv0; s[1][1] += qv1 * kv1; s[1][2] += qv1 * kv2; s[1][3] += qv1 * kv3;
        s[2][0] += qv2 * kv0; s[2][1] += qv2 * kv1; s[2][2] += qv2 * kv2; s[2][3] += qv2 * kv3;
        s[3][0] += qv3 * kv0; s[3][1] += qv3 * kv1; s[3][2] += qv3 * kv2; s[3][3] += qv3 * kv3;
    }
    #pragma unroll
    for (int i = 0; i < 4; i++) {
        int q = qBase + ty4 + i;
        const int* mrow = mask + ((size_t)(b * SEQ + q)) * SEQ;
        float* srow = scores + (((size_t)(b * HEADS + h)) * SEQ + q) * SEQ;
        #pragma unroll
        for (int j = 0; j < 4; j++) {
            int kk = kkBase + tx4 + j;
            srow[kk] = (mrow[kk] == 0) ? NEGV : s[i][j] * 0.125f;
        }
    }
}

extern "C" void kernel_launch(void* const* d_in, const int* in_sizes, int n_in,
                              void* d_out, int out_size, void* d_ws, size_t ws_size,
                              hipStream_t stream)
{
    const float* x   = (const float*)d_in[0];
    const int*   msk = (const int*)d_in[1];
    const float* Wq  = (const float*)d_in[2];
    const float* bq  = (const float*)d_in[3];
    const float* Wk  = (const float*)d_in[4];
    const float* bk  = (const float*)d_in[5];
    const float* Wv  = (const float*)d_in[6];
    const float* bv  = (const float*)d_in[7];
    const float* Wo  = (const float*)d_in[8];
    const float* bo  = (const float*)d_in[9];
    const float* lng = (const float*)d_in[10];
    const float* lnb = (const float*)d_in[11];

    float* out0   = (float*)d_out;                 // chunk 0: [B*S, HIDDEN]
    float* scores = out0 + (size_t)TOK;            // chunk 1: [B,H,S,S]

    const size_t need = (size_t)3 * TOK * sizeof(float);   // 48 MiB: K/V/ctx splits
    const bool use_ws = (d_ws != nullptr) && (ws_size >= need);

    const int M = BATCH * SEQ;

    if (use_ws) {
        // ws: K/V/ctx splits (6 x 8 MB = 48 MiB exact).
        unsigned short* Khi = (unsigned short*)d_ws;
        unsigned short* Klo = Khi + (size_t)TOK;
        unsigned short* Vhi = Klo + (size_t)TOK;
        unsigned short* Vlo = Vhi + (size_t)TOK;
        unsigned short* Chi = Vlo + (size_t)TOK;
        unsigned short* Clo = Chi + (size_t)TOK;
        // out0: Q split (16 MB exact; dead before Wo GEMM writes out0).
        unsigned short* Qhi = (unsigned short*)out0;
        unsigned short* Qlo = Qhi + (size_t)TOK;
        // scores region: pre-attention scratch (x split + fused W^T splits, ~29 MB).
        unsigned short* Xhi = (unsigned short*)scores;
        unsigned short* Xlo = Xhi + (size_t)TOK;
        unsigned short* WTh = Xlo + (size_t)TOK;        // [3*HIDDEN][HIDDEN] rows: q,k,v
        unsigned short* WTl = WTh + (size_t)3 * HH;
        // Wo^T split: carved from dead K region of ws AFTER attention (4 MB < 8 MB).
        unsigned short* WToh = Khi;
        unsigned short* WTol = Khi + (size_t)HH;

        split_rows<<<TOK / (256 * 8), 256, 0, stream>>>(x, Xhi, Xlo);
        dim3 gt(16, 16);
        split_T<<<gt, 256, 0, stream>>>(Wq, WTh, WTl);
        split_T<<<gt, 256, 0, stream>>>(Wk, WTh + (size_t)HH, WTl + (size_t)HH);
        split_T<<<gt, 256, 0, stream>>>(Wv, WTh + (size_t)2 * HH, WTl + (size_t)2 * HH);

        // fused QKV projection: N = 3072
        dim3 gf(3 * HIDDEN / 128, M / 128);   // (24, 32) = 768 blocks
        gemm_ps<1><<<gf, 512, 0, stream>>>(Xhi, Xlo, WTh, WTl,
                                           bq, bk, bv, nullptr,
                                           Qhi, Qlo, Khi, Klo, Vhi, Vlo, M);
        attn_mfma<<<dim3(SEQ / 64, HEADS, BATCH), 256, 0, stream>>>(
            Qhi, Qlo, Khi, Klo, Vhi, Vlo, msk, scores, Chi, Clo);
        split_T<<<gt, 256, 0, stream>>>(Wo, WToh, WTol);
        dim3 go(HIDDEN / 128, M / 128);       // (8, 32)
        gemm_ps<0><<<go, 512, 0, stream>>>(Chi, Clo, WToh, WTol,
                                           bo, nullptr, nullptr, out0,
                                           nullptr, nullptr, nullptr, nullptr, nullptr, nullptr, M);
        ln_kernel<<<M, 256, 0, stream>>>(out0, x, lng, lnb, out0);
    } else {
        // fp32 fallback (scratch carved from score tail + fixup)
        float* Ks = scores + (SC_N - (size_t)3 * TOK);
        float* Vs = Ks + (size_t)TOK;
        float* Cs = Vs + (size_t)TOK;
        float* Qs = out0;
        dim3 gg(HIDDEN / 64, M / 64);
        gemm_bias<<<gg, 256, 0, stream>>>(x, Wq, bq, Qs, M, HIDDEN, HIDDEN);
        gemm_bias<<<gg, 256, 0, stream>>>(x, Wk, bk, Ks, M, HIDDEN, HIDDEN);
        gemm_bias<<<gg, 256, 0, stream>>>(x, Wv, bv, Vs, M, HIDDEN, HIDDEN);
        attn_kernel<<<dim3(SEQ, HEADS, BATCH), 256, 0, stream>>>(Qs, Ks, Vs, msk, scores, Cs, ROW_CUT);
        gemm_bias<<<gg, 256, 0, stream>>>(Cs, Wo, bo, out0, M, HIDDEN, HIDDEN);
        ln_kernel<<<M, 256, 0, stream>>>(out0, x, lng, lnb, out0);
        score_fixup<<<dim3(SEQ / 64, SEQ / 64, 3), 256, 0, stream>>>(x, Wq, bq, Wk, bk, msk, scores);
    }
}